// Round 4
// baseline (906.482 us; speedup 1.0000x reference)
//
#include <hip/hip_runtime.h>

// RadarRnn1: 4-layer tanh RNN (B=512,S=1024,IN=64,H=32) + per-step FC + softmax over S.
// R4: kill the s_barrier entirely. R3 showed 1 block/CU -> the block-wide barrier
// makes tick = slowest wave's full latency chain (~1430cy vs ~490cy of VALU issue).
// New shape: one wave per batch element (block=64, grid=512), all 4 layers inside
// the wave with the t=T-l skew (independent within a tick), h handoff via
// wave-local LDS (DS ops are in-order within a wave; lgkmcnt only, no barrier).
// Logits stage in LDS, flushed as one coalesced store per 64 ticks.

#define BB 512
#define SS 1024
#define INF 64
#define HH 32
#define LL 4

// v = v + dpp_mov(v, CTRL); bound_ctrl=1 -> out-of-range lanes contribute 0.
template <int CTRL>
__device__ __forceinline__ float dpp_add(float v) {
  int y = __builtin_amdgcn_update_dpp(0, __float_as_int(v), CTRL, 0xF, 0xF, true);
  return v + __int_as_float(y);
}

typedef const __attribute__((address_space(1))) void* gptr_t;
typedef __attribute__((address_space(3))) void* lptr_t;

__global__ __launch_bounds__(64) void rnn_kernel(
    const float* __restrict__ x, const float* __restrict__ h_state,
    const float* __restrict__ W_ih0, const float* __restrict__ W_ih_rest,
    const float* __restrict__ W_hh, const float* __restrict__ b_ih,
    const float* __restrict__ b_hh, const float* __restrict__ fc_w,
    const float* __restrict__ fc_b, float* __restrict__ out) {
  __shared__ float hbuf[2][LL][HH];  // [parity][layer][h]
  __shared__ float xring[8][INF];    // x slot ring, filled by global_load_lds
  __shared__ float lbuf[64];         // logit staging (flushed every 64 ticks)

  const int lane = threadIdx.x;  // 64
  const int b    = blockIdx.x;   // one batch element per wave
  const int ks   = lane & 1;     // k-split half
  const int h    = lane >> 1;    // output unit 0..31

  // ---------------- weights into registers (144 floats/lane) ----------------
  float4 w0x[8], w0h[4], wi[3][4], wh[3][4];
  {
    const float4* p = (const float4*)(W_ih0 + h * INF + ks * 32);
#pragma unroll
    for (int j = 0; j < 8; ++j) w0x[j] = p[j];
    const float4* q = (const float4*)(W_hh + h * HH + ks * 16);
#pragma unroll
    for (int j = 0; j < 4; ++j) w0h[j] = q[j];
#pragma unroll
    for (int l = 1; l < LL; ++l) {
      const float4* pi = (const float4*)(W_ih_rest + ((l - 1) * HH + h) * HH + ks * 16);
      const float4* ph = (const float4*)(W_hh + (l * HH + h) * HH + ks * 16);
#pragma unroll
      for (int j = 0; j < 4; ++j) { wi[l - 1][j] = pi[j]; wh[l - 1][j] = ph[j]; }
    }
  }
  float bias[LL];
#pragma unroll
  for (int l = 0; l < LL; ++l) bias[l] = b_ih[l * HH + h] + b_hh[l * HH + h];
  const float fcwh = fc_w[h] * 0.5f;  // both ks lanes hold hval -> 64-lane sum is 2x
  const float fcb  = fc_b[0];

  // initial hidden state -> parity 1 (first read parity for every layer)
  if (ks == 0) {
#pragma unroll
    for (int l = 0; l < LL; ++l) hbuf[1][l][h] = h_state[(l * BB + b) * HH + h];
  }
  // single wave: DS ops are in-order, no barrier needed anywhere.

  const float* xb = x + (size_t)b * SS * INF;
#pragma unroll
  for (int j = 0; j < 6; ++j)  // prefill: 6 in-flight global_load_lds
    __builtin_amdgcn_global_load_lds((gptr_t)(xb + j * INF + lane),
                                     (lptr_t)&xring[j][0], 4, 0, 0);

  float* const outrow = out + (size_t)b * SS;
  float* const hfin   = out + (size_t)BB * SS;

  // Parities (par = T&1): layer l input h_{l-1}^{T-l} parity par^(l&1);
  // own history h_l^{T-l-1} parity par^(l&1)^1; write h_l^{T-l} parity par^(l&1).
  auto tick = [&](int T, int par, bool A0, bool A1, bool A2, bool A3)
      __attribute__((always_inline)) {
    float4 xv[8], h0v[4], i1[4], h1v[4], i2[4], h2v[4], i3[4], h3v[4];
    if (A0) {
      // oldest of 6 in-flight x loads = slot T&7. Any wait with >=6 outstanding
      // drains the oldest, so extra stores in the queue only over-wait.
      asm volatile("s_waitcnt vmcnt(5)" ::: "memory");
      const float4* xs = (const float4*)&xring[T & 7][ks * 32];
#pragma unroll
      for (int j = 0; j < 8; ++j) xv[j] = xs[j];
      const float4* p = (const float4*)&hbuf[par ^ 1][0][ks * 16];
#pragma unroll
      for (int j = 0; j < 4; ++j) h0v[j] = p[j];
    }
    if (A1) {
      const float4* pi = (const float4*)&hbuf[par ^ 1][0][ks * 16];
      const float4* ph = (const float4*)&hbuf[par][1][ks * 16];
#pragma unroll
      for (int j = 0; j < 4; ++j) { i1[j] = pi[j]; h1v[j] = ph[j]; }
    }
    if (A2) {
      const float4* pi = (const float4*)&hbuf[par][1][ks * 16];
      const float4* ph = (const float4*)&hbuf[par ^ 1][2][ks * 16];
#pragma unroll
      for (int j = 0; j < 4; ++j) { i2[j] = pi[j]; h2v[j] = ph[j]; }
    }
    if (A3) {
      const float4* pi = (const float4*)&hbuf[par ^ 1][2][ks * 16];
      const float4* ph = (const float4*)&hbuf[par][3][ks * 16];
#pragma unroll
      for (int j = 0; j < 4; ++j) { i3[j] = pi[j]; h3v[j] = ph[j]; }
    }
    if (T < SS) {  // keep exactly one new load per active tick (clamped dup at tail)
      int tl = T + 6; tl = (tl < SS) ? tl : (SS - 1);
      __builtin_amdgcn_global_load_lds((gptr_t)(xb + tl * INF + lane),
                                       (lptr_t)&xring[(T + 6) & 7][0], 4, 0, 0);
    }
    if (A0) {
      float a0 = 0.f, a1 = 0.f, a2 = 0.f, a3 = 0.f;
#pragma unroll
      for (int j = 0; j < 8; ++j) {
        a0 += w0x[j].x * xv[j].x; a1 += w0x[j].y * xv[j].y;
        a2 += w0x[j].z * xv[j].z; a3 += w0x[j].w * xv[j].w;
      }
#pragma unroll
      for (int j = 0; j < 4; ++j) {
        a0 += w0h[j].x * h0v[j].x; a1 += w0h[j].y * h0v[j].y;
        a2 += w0h[j].z * h0v[j].z; a3 += w0h[j].w * h0v[j].w;
      }
      float acc = ((a0 + a1) + (a2 + a3));
      acc = dpp_add<0xB1>(acc) + bias[0];
      const float e  = __expf(2.0f * acc);
      const float hv = 1.0f - 2.0f / (e + 1.0f);
      if (ks == 0) hbuf[par][0][h] = hv;
      if (T == SS - 1 && ks == 0) hfin[(0 * BB + b) * HH + h] = hv;
    }
    if (A1) {
      float a0 = 0.f, a1 = 0.f, a2 = 0.f, a3 = 0.f;
#pragma unroll
      for (int j = 0; j < 4; ++j) {
        a0 += wi[0][j].x * i1[j].x; a1 += wi[0][j].y * i1[j].y;
        a2 += wi[0][j].z * i1[j].z; a3 += wi[0][j].w * i1[j].w;
        a0 += wh[0][j].x * h1v[j].x; a1 += wh[0][j].y * h1v[j].y;
        a2 += wh[0][j].z * h1v[j].z; a3 += wh[0][j].w * h1v[j].w;
      }
      float acc = ((a0 + a1) + (a2 + a3));
      acc = dpp_add<0xB1>(acc) + bias[1];
      const float e  = __expf(2.0f * acc);
      const float hv = 1.0f - 2.0f / (e + 1.0f);
      if (ks == 0) hbuf[par ^ 1][1][h] = hv;
      if (T - 1 == SS - 1 && ks == 0) hfin[(1 * BB + b) * HH + h] = hv;
    }
    if (A2) {
      float a0 = 0.f, a1 = 0.f, a2 = 0.f, a3 = 0.f;
#pragma unroll
      for (int j = 0; j < 4; ++j) {
        a0 += wi[1][j].x * i2[j].x; a1 += wi[1][j].y * i2[j].y;
        a2 += wi[1][j].z * i2[j].z; a3 += wi[1][j].w * i2[j].w;
        a0 += wh[1][j].x * h2v[j].x; a1 += wh[1][j].y * h2v[j].y;
        a2 += wh[1][j].z * h2v[j].z; a3 += wh[1][j].w * h2v[j].w;
      }
      float acc = ((a0 + a1) + (a2 + a3));
      acc = dpp_add<0xB1>(acc) + bias[2];
      const float e  = __expf(2.0f * acc);
      const float hv = 1.0f - 2.0f / (e + 1.0f);
      if (ks == 0) hbuf[par][2][h] = hv;
      if (T - 2 == SS - 1 && ks == 0) hfin[(2 * BB + b) * HH + h] = hv;
    }
    if (A3) {
      float a0 = 0.f, a1 = 0.f, a2 = 0.f, a3 = 0.f;
#pragma unroll
      for (int j = 0; j < 4; ++j) {
        a0 += wi[2][j].x * i3[j].x; a1 += wi[2][j].y * i3[j].y;
        a2 += wi[2][j].z * i3[j].z; a3 += wi[2][j].w * i3[j].w;
        a0 += wh[2][j].x * h3v[j].x; a1 += wh[2][j].y * h3v[j].y;
        a2 += wh[2][j].z * h3v[j].z; a3 += wh[2][j].w * h3v[j].w;
      }
      float acc = ((a0 + a1) + (a2 + a3));
      acc = dpp_add<0xB1>(acc) + bias[3];
      const float e  = __expf(2.0f * acc);
      const float hv = 1.0f - 2.0f / (e + 1.0f);
      if (ks == 0) hbuf[par ^ 1][3][h] = hv;
      const int t3 = T - 3;
      if (t3 == SS - 1 && ks == 0) hfin[(3 * BB + b) * HH + h] = hv;
      // FC: DPP cascade (lane 63 ends with the 64-lane sum), stage in LDS.
      float v = hv * fcwh;
      v = dpp_add<0x111>(v);  // row_shr:1
      v = dpp_add<0x112>(v);  // row_shr:2
      v = dpp_add<0x114>(v);  // row_shr:4
      v = dpp_add<0x118>(v);  // row_shr:8
      v = dpp_add<0x142>(v);  // row_bcast:15
      v = dpp_add<0x143>(v);  // row_bcast:31
      if (lane == 63) lbuf[t3 & 63] = v + fcb;
      if ((t3 & 63) == 63) {  // coalesced flush of 64 logits
        float lv = lbuf[lane];
        outrow[t3 - 63 + lane] = lv;
      }
    }
  };

  // prologue (layers come online one per tick)
  tick(0, 0, true, false, false, false);
  tick(1, 1, true, true, false, false);
  tick(2, 0, true, true, true, false);
  tick(3, 1, true, true, true, true);
  // steady: T = 4 .. SS-1 (1020 ticks, even), parity compile-time via unroll-2
  for (int T = 4; T < SS; T += 2) {
    tick(T, 0, true, true, true, true);
    tick(T + 1, 1, true, true, true, true);
  }
  // drain
  tick(SS, 0, false, true, true, true);
  tick(SS + 1, 1, false, false, true, true);
  tick(SS + 2, 0, false, false, false, true);
}

__global__ __launch_bounds__(256) void softmax_kernel(float* __restrict__ out) {
  __shared__ float red[8];
  const int row = blockIdx.x;
  float* p = out + (size_t)row * SS;
  const int tid = threadIdx.x;
  float4 v = ((const float4*)p)[tid];  // 256 threads x 4 = 1024 logits
  float m = fmaxf(fmaxf(v.x, v.y), fmaxf(v.z, v.w));
#pragma unroll
  for (int d = 32; d >= 1; d >>= 1) m = fmaxf(m, __shfl_xor(m, d));
  if ((tid & 63) == 0) red[tid >> 6] = m;
  __syncthreads();
  m = fmaxf(fmaxf(red[0], red[1]), fmaxf(red[2], red[3]));
  const float e0 = __expf(v.x - m), e1 = __expf(v.y - m);
  const float e2 = __expf(v.z - m), e3 = __expf(v.w - m);
  float s = (e0 + e1) + (e2 + e3);
#pragma unroll
  for (int d = 32; d >= 1; d >>= 1) s += __shfl_xor(s, d);
  if ((tid & 63) == 0) red[4 + (tid >> 6)] = s;
  __syncthreads();
  s = (red[4] + red[5]) + (red[6] + red[7]);
  const float inv = 1.0f / s;
  float4 o;
  o.x = e0 * inv; o.y = e1 * inv; o.z = e2 * inv; o.w = e3 * inv;
  ((float4*)p)[tid] = o;
}

extern "C" void kernel_launch(void* const* d_in, const int* in_sizes, int n_in,
                              void* d_out, int out_size, void* d_ws, size_t ws_size,
                              hipStream_t stream) {
  const float* x         = (const float*)d_in[0];
  const float* h_state   = (const float*)d_in[1];
  const float* W_ih0     = (const float*)d_in[2];
  const float* W_ih_rest = (const float*)d_in[3];
  const float* W_hh      = (const float*)d_in[4];
  const float* b_ih      = (const float*)d_in[5];
  const float* b_hh      = (const float*)d_in[6];
  const float* fc_w      = (const float*)d_in[7];
  const float* fc_b      = (const float*)d_in[8];
  float* out = (float*)d_out;

  hipLaunchKernelGGL(rnn_kernel, dim3(BB), dim3(64), 0, stream,
                     x, h_state, W_ih0, W_ih_rest, W_hh, b_ih, b_hh, fc_w, fc_b, out);
  hipLaunchKernelGGL(softmax_kernel, dim3(BB), dim3(256), 0, stream, out);
}